// Round 7
// baseline (100.531 us; speedup 1.0000x reference)
//
#include <hip/hip_runtime.h>

#define BATCH 4
#define T 4096
#define D 128
#define NP 16                  // K-split partials per strip (K = 256 rows each)
#define NS 4                   // column strips of G
#define SW 32                  // strip width (cols)
#define KR 256                 // rows per partial
#define ROWS 64                // rows per staging chunk / per stage-2 block
#define ST1 72                 // XT LDS stride in ushorts (144 B = 36 words == 4 mod 32)
#define S2 136                 // row-major LDS stride in ushorts (272 B)

typedef __attribute__((ext_vector_type(4))) float f32x4;
typedef __attribute__((ext_vector_type(8))) short bf16x8;

// float -> bf16 bits, round-to-nearest-even
__device__ __forceinline__ unsigned short f2b(float f) {
    unsigned u = __builtin_bit_cast(unsigned, f);
    u += 0x7FFFu + ((u >> 16) & 1u);
    return (unsigned short)(u >> 16);
}

// Proven staging: 64 rows x 128 cols f32 -> transposed bf16 XT[d][t].
// 8 passes x 256 threads x 16 B; banks <=2-way (free).
#define STAGE_CHUNK(XPBASE, DST)                                               \
    {                                                                          \
        _Pragma("unroll")                                                      \
        for (int pass = 0; pass < 8; pass++) {                                 \
            const int slot = (tid >> 6) + 4 * pass;                            \
            const int dd = 2 * (tid & 7) + 16 * (slot & 7);                    \
            const int tpg = ((tid >> 3) & 7) + 8 * (slot >> 3);                \
            const int t = 2 * tpg;                                             \
            float2 f0 = *(const float2*)((XPBASE) + (size_t)t * D + dd);       \
            float2 f1 = *(const float2*)((XPBASE) + (size_t)(t + 1) * D + dd); \
            unsigned u0 = (unsigned)f2b(f0.x) | ((unsigned)f2b(f1.x) << 16);   \
            unsigned u1 = (unsigned)f2b(f0.y) | ((unsigned)f2b(f1.y) << 16);   \
            *(unsigned*)((DST) + dd * ST1 + 2 * tpg) = u0;                     \
            *(unsigned*)((DST) + (dd + 1) * ST1 + 2 * tpg) = u1;               \
        }                                                                      \
    }

// ---------------- Kernel 1: strip partials of G -----------------
// 256 blocks x 256 threads; block (b, p, s) computes partial
// G[:, s*32 .. s*32+32) over X rows [p*256, p*256+256), i.e. a 128x32
// bf16 tile. 4 chunk iterations (64 rows each), double-buffered LDS,
// runtime loop (proven R5 no-spill pattern). Wave w: m-tiles {2w,2w+1}
// x 2 n-tiles; 8 MFMA per chunk per wave (32 total — same as R0 k_gram).
__global__ __launch_bounds__(256) void k_gram_strip(const float* __restrict__ x,
                                                    unsigned short* __restrict__ part) {
    __shared__ unsigned short XT[2 * D * ST1];   // double-buffered, 36.9 KB
    const int blk = blockIdx.x;                  // ((b*16 + p)*4) + s
    const int s = blk & 3, p = (blk >> 2) & 15, b = blk >> 6;
    const float* xp = x + ((size_t)b * T + (size_t)p * KR) * D;
    const int tid = threadIdx.x;
    const int lane = tid & 63, w = tid >> 6;
    const int m = lane & 15, q = lane >> 4;
    const int m0 = w * 32;

    f32x4 acc[2][2];
    #pragma unroll
    for (int mi = 0; mi < 2; mi++)
        #pragma unroll
        for (int ni = 0; ni < 2; ni++) acc[mi][ni] = (f32x4){0.f, 0.f, 0.f, 0.f};

    STAGE_CHUNK(xp, XT);                         // chunk 0 -> buf 0
    __syncthreads();

    #pragma unroll 1
    for (int i = 0; i < 4; i++) {
        const unsigned short* cur = XT + (i & 1) * (D * ST1);
        unsigned short* nxt = XT + ((i + 1) & 1) * (D * ST1);
        if (i < 3) {                             // prefetch next chunk -> other buf
            const float* xn = xp + (size_t)(i + 1) * ROWS * D;
            STAGE_CHUNK(xn, nxt);
        }
        #pragma unroll
        for (int ks = 0; ks < 2; ks++) {         // K=64 per chunk, 2 k-steps
            bf16x8 av[2], bv[2];
            #pragma unroll
            for (int mi = 0; mi < 2; mi++)
                av[mi] = *(const bf16x8*)(cur + (m0 + mi * 16 + m) * ST1 + q * 8 + ks * 32);
            #pragma unroll
            for (int ni = 0; ni < 2; ni++)
                bv[ni] = *(const bf16x8*)(cur + (s * SW + ni * 16 + m) * ST1 + q * 8 + ks * 32);
            #pragma unroll
            for (int mi = 0; mi < 2; mi++)
                #pragma unroll
                for (int ni = 0; ni < 2; ni++)
                    acc[mi][ni] = __builtin_amdgcn_mfma_f32_16x16x32_bf16(av[mi], bv[ni], acc[mi][ni], 0, 0, 0);
        }
        __syncthreads();
    }

    // Store 128x32 bf16 partial. C/D layout: col=lane&15, row=q*4+reg (m89/m91).
    unsigned short* pp = part + (size_t)blk * (D * SW);
    #pragma unroll
    for (int mi = 0; mi < 2; mi++)
        #pragma unroll
        for (int ni = 0; ni < 2; ni++) {
            const int row0 = m0 + mi * 16 + q * 4;
            const int col = ni * 16 + m;
            #pragma unroll
            for (int r = 0; r < 4; r++)
                pp[(size_t)(row0 + r) * SW + col] = f2b(acc[mi][ni][r]);
        }
}

// ---------------- Kernel 2: fused 16-way strip reduce + out = X*G ------------
// 256 blocks x 256 threads; block = (batch, 64-row chunk), batch->2-XCD
// grouping (proven R4) keeps the batch's 512 KB of partials L2-resident.
// Gs staging = f32 reduction over NP=16 strip partials; then the verbatim
// proven k_xg MFMA phase (G symmetric: B-fragments read G row-major).
__global__ __launch_bounds__(256) void k_xg3(const float* __restrict__ x,
                                             const unsigned short* __restrict__ part,
                                             float* __restrict__ out) {
    __shared__ unsigned short Xs[ROWS * S2];   // 17.4 KB
    __shared__ unsigned short Gs[D * S2];      // 34.8 KB
    const int blk = blockIdx.x;
    const int b = (blk & 7) >> 1;
    const int chunk = ((blk & 1) << 5) | (blk >> 3);   // 0..63, bijective per batch
    const float* xp = x + ((size_t)b * T + (size_t)chunk * ROWS) * D;
    const int tid = threadIdx.x;

    // Xs staging (proven): 64 rows f32 -> bf16 row-major
    {
        const int dg = tid & 31, tr = tid >> 5;
        #pragma unroll
        for (int ii = 0; ii < 8; ii++) {
            const int t = tr + ii * 8;
            float4 v = ((const float4*)(xp + (size_t)t * D))[dg];
            ushort4 pk;
            pk.x = f2b(v.x); pk.y = f2b(v.y); pk.z = f2b(v.z); pk.w = f2b(v.w);
            *(ushort4*)(Xs + t * S2 + dg * 4) = pk;
        }
    }
    // Gs staging fused with the strip-partial reduction (f32 accumulate).
    // Group g (8 consecutive G elts in one strip): s=g>>9, row=(g&511)>>2,
    // c32=(g&3)*8. A wave's 64 lanes cover 4 KB contiguous per (s,p) stream.
    {
        #pragma unroll 2
        for (int i = 0; i < 8; i++) {
            const int g = i * 256 + tid;           // 0..2047
            const int s = g >> 9;
            const int rem = g & 511;
            const int row = rem >> 2;
            const int c32 = (rem & 3) * 8;
            const unsigned short* pb = part + (size_t)((b * 16) * 4 + s) * (D * SW)
                                     + (size_t)row * SW + c32;
            float acc8[8];
            #pragma unroll
            for (int k = 0; k < 8; k++) acc8[k] = 0.f;
            #pragma unroll
            for (int p = 0; p < NP; p++) {
                uint4 v = *(const uint4*)(pb + (size_t)p * 4 * (D * SW));
                const unsigned uu[4] = {v.x, v.y, v.z, v.w};
                #pragma unroll
                for (int k = 0; k < 4; k++) {
                    acc8[2 * k]     += __builtin_bit_cast(float, uu[k] << 16);
                    acc8[2 * k + 1] += __builtin_bit_cast(float, uu[k] & 0xFFFF0000u);
                }
            }
            uint4 o;
            o.x = (unsigned)f2b(acc8[0]) | ((unsigned)f2b(acc8[1]) << 16);
            o.y = (unsigned)f2b(acc8[2]) | ((unsigned)f2b(acc8[3]) << 16);
            o.z = (unsigned)f2b(acc8[4]) | ((unsigned)f2b(acc8[5]) << 16);
            o.w = (unsigned)f2b(acc8[6]) | ((unsigned)f2b(acc8[7]) << 16);
            *(uint4*)(Gs + row * S2 + s * SW + c32) = o;
        }
    }
    __syncthreads();

    // Proven k_xg MFMA phase: out(64x128) = Xs . G
    {
        const int lane = tid & 63, w = tid >> 6;
        const int m = lane & 15, q = lane >> 4;
        f32x4 acc[8];
        #pragma unroll
        for (int ni = 0; ni < 8; ni++) acc[ni] = (f32x4){0.f, 0.f, 0.f, 0.f};

        const unsigned short* arow = Xs + (w * 16 + m) * S2 + q * 8;
        const unsigned short* brow = Gs + m * S2 + q * 8;

        #pragma unroll
        for (int ks = 0; ks < 4; ks++) {
            bf16x8 a = *(const bf16x8*)(arow + ks * 32);
            #pragma unroll
            for (int ni = 0; ni < 8; ni++) {
                bf16x8 bb = *(const bf16x8*)(brow + ni * 16 * S2 + ks * 32);
                acc[ni] = __builtin_amdgcn_mfma_f32_16x16x32_bf16(a, bb, acc[ni], 0, 0, 0);
            }
        }

        float* op = out + ((size_t)b * T + (size_t)chunk * ROWS) * D;
        const int row0 = w * 16 + q * 4;
        #pragma unroll
        for (int ni = 0; ni < 8; ni++)
            #pragma unroll
            for (int r = 0; r < 4; r++)
                op[(row0 + r) * D + ni * 16 + m] = acc[ni][r];
    }
}

extern "C" void kernel_launch(void* const* d_in, const int* in_sizes, int n_in,
                              void* d_out, int out_size, void* d_ws, size_t ws_size,
                              hipStream_t stream) {
    const float* x = (const float*)d_in[0];
    float* out = (float*)d_out;

    // Workspace: 256 strip partials x 128x32 bf16 = 2 MB. No counters, no
    // memset, no barriers — the single kernel boundary is the sync.
    unsigned short* part = (unsigned short*)d_ws;

    k_gram_strip<<<BATCH * NP * NS, 256, 0, stream>>>(x, part);
    k_xg3<<<BATCH * 64, 256, 0, stream>>>(x, part, out);
}

// Round 8
// 69.795 us; speedup vs baseline: 1.4404x; 1.4404x over previous
//
#include <hip/hip_runtime.h>

#define BATCH 4
#define T 4096
#define D 128
#define CHUNKS 64              // gram chunks per batch (64 rows each)
#define ROWS1 64               // rows per gram block
#define ROWS2 64               // rows per stage-2 block
#define ST1 72                 // XT LDS stride in ushorts (144 B = 36 words == 4 mod 32)
#define S2 136                 // stage-2 LDS stride in ushorts (272 B)

typedef __attribute__((ext_vector_type(4))) float f32x4;
typedef __attribute__((ext_vector_type(8))) short bf16x8;

// float -> bf16 bits, round-to-nearest-even
__device__ __forceinline__ unsigned short f2b(float f) {
    unsigned u = __builtin_bit_cast(unsigned, f);
    u += 0x7FFFu + ((u >> 16) & 1u);
    return (unsigned short)(u >> 16);
}
__device__ __forceinline__ float b2f(unsigned short h) {
    return __builtin_bit_cast(float, (unsigned)h << 16);
}

// ---------------- Stage 1: partial Gram via bf16 MFMA -----------------
// 256 blocks x 256 threads; block = (batch, 64-row chunk).
// LDS holds XT[d][t] (transposed, bf16): both A (=X^T row-major) and
// B (B^T = X^T row-major, m92 trick) fragments of G = X^T X read it
// contiguously in k=t. Transpose happens on the staging write: thread
// loads float2 from rows t,t+1 (64B-coalesced), packs 2 uints, writes
// word (36d + tp) -> banks (8*(lane&7) + tp) mod 32, <=2-way = free.
// Wave w computes m-tiles {2w,2w+1} x 8 n-tiles, K=64 in 2 MFMA steps.
__global__ __launch_bounds__(256) void k_gram(const float* __restrict__ x,
                                              unsigned short* __restrict__ part) {
    __shared__ unsigned short XT[D * ST1];   // 18.4 KB
    const int blk = blockIdx.x;
    const int b = blk >> 6, chunk = blk & 63;
    const float* xp = x + ((size_t)b * T + (size_t)chunk * ROWS1) * D;
    const int tid = threadIdx.x;

    #pragma unroll
    for (int pass = 0; pass < 8; pass++) {
        const int slot = (tid >> 6) + 4 * pass;      // 0..31
        const int dd = 2 * (tid & 7) + 16 * (slot & 7);    // even d base, 0..126
        const int tpg = ((tid >> 3) & 7) + 8 * (slot >> 3); // t-pair 0..31
        const int t = 2 * tpg;
        float2 f0 = *(const float2*)(xp + (size_t)t * D + dd);
        float2 f1 = *(const float2*)(xp + (size_t)(t + 1) * D + dd);
        unsigned u0 = (unsigned)f2b(f0.x) | ((unsigned)f2b(f1.x) << 16);
        unsigned u1 = (unsigned)f2b(f0.y) | ((unsigned)f2b(f1.y) << 16);
        *(unsigned*)(XT + dd * ST1 + 2 * tpg) = u0;        // XT[dd][t..t+1]
        *(unsigned*)(XT + (dd + 1) * ST1 + 2 * tpg) = u1;  // XT[dd+1][t..t+1]
    }
    __syncthreads();

    const int lane = tid & 63, w = tid >> 6;
    const int m = lane & 15, q = lane >> 4;
    const int m0 = w * 32;

    f32x4 acc[2][8];
    #pragma unroll
    for (int mi = 0; mi < 2; mi++)
        #pragma unroll
        for (int ni = 0; ni < 8; ni++) acc[mi][ni] = (f32x4){0.f, 0.f, 0.f, 0.f};

    #pragma unroll
    for (int s = 0; s < 2; s++) {            // k0 = s*32
        bf16x8 av[2], bv[8];
        #pragma unroll
        for (int mi = 0; mi < 2; mi++)
            av[mi] = *(const bf16x8*)(XT + (m0 + mi * 16 + m) * ST1 + q * 8 + s * 32);
        #pragma unroll
        for (int ni = 0; ni < 8; ni++)
            bv[ni] = *(const bf16x8*)(XT + (ni * 16 + m) * ST1 + q * 8 + s * 32);
        #pragma unroll
        for (int mi = 0; mi < 2; mi++)
            #pragma unroll
            for (int ni = 0; ni < 8; ni++)
                acc[mi][ni] = __builtin_amdgcn_mfma_f32_16x16x32_bf16(av[mi], bv[ni], acc[mi][ni], 0, 0, 0);
    }

    // Store partial G (bf16). C/D layout: col=lane&15, row=q*4+reg (m89/m91).
    unsigned short* pp = part + (size_t)blk * (D * D);
    #pragma unroll
    for (int mi = 0; mi < 2; mi++)
        #pragma unroll
        for (int ni = 0; ni < 8; ni++) {
            const int row0 = m0 + mi * 16 + q * 4;
            const int col = ni * 16 + m;
            #pragma unroll
            for (int r = 0; r < 4; r++)
                pp[(size_t)(row0 + r) * D + col] = f2b(acc[mi][ni][r]);
        }
}

// ---------------- Stage 1b: reduce bf16 partials -> bf16 G -----------------
// 256 blocks x 256 threads; one G element/thread, 8 independent accumulators.
__global__ __launch_bounds__(256) void k_reduce_g(const unsigned short* __restrict__ part,
                                                  unsigned short* __restrict__ g) {
    const int o = blockIdx.x * 256 + threadIdx.x;   // 0 .. BATCH*D*D
    const int b = o >> 14;
    const int e = o & 16383;
    const unsigned short* p = part + ((size_t)b * CHUNKS) * (D * D) + e;
    float s[8];
    #pragma unroll
    for (int i = 0; i < 8; i++) s[i] = 0.f;
    for (int c = 0; c < CHUNKS; c += 8) {
        #pragma unroll
        for (int i = 0; i < 8; i++)
            s[i] += b2f(p[(size_t)(c + i) * (D * D)]);
    }
    float sum = ((s[0] + s[1]) + (s[2] + s[3])) + ((s[4] + s[5]) + (s[6] + s[7]));
    g[o] = f2b(sum);
}

// ---------------- Stage 2: out = X * G via bf16 MFMA -----------------
// (proven: 8.9 us win, absmax 128)
__global__ __launch_bounds__(256) void k_xg_mfma(const float* __restrict__ x,
                                                 const unsigned short* __restrict__ g,
                                                 float* __restrict__ out) {
    __shared__ unsigned short Xs[ROWS2 * S2];   // 17.4 KB
    __shared__ unsigned short Gs[D * S2];       // 34.8 KB
    const int blk = blockIdx.x;
    const int b = blk >> 6, chunk = blk & 63;
    const float* xp = x + ((size_t)b * T + (size_t)chunk * ROWS2) * D;
    const unsigned short* gp = g + (size_t)b * (D * D);
    const int tid = threadIdx.x;

    {
        const int dg = tid & 31, tr = tid >> 5;
        #pragma unroll
        for (int ii = 0; ii < 8; ii++) {
            const int t = tr + ii * 8;
            float4 v = ((const float4*)(xp + t * D))[dg];
            ushort4 pk;
            pk.x = f2b(v.x); pk.y = f2b(v.y); pk.z = f2b(v.z); pk.w = f2b(v.w);
            *(ushort4*)(Xs + t * S2 + dg * 4) = pk;
        }
    }
    {
        const int f4 = tid & 15, r = tid >> 4;
        #pragma unroll
        for (int ii = 0; ii < 8; ii++) {
            const int row = r + ii * 16;
            uint4 gv = ((const uint4*)(gp + row * D))[f4];
            *(uint4*)(Gs + row * S2 + f4 * 8) = gv;
        }
    }
    __syncthreads();

    const int lane = tid & 63, w = tid >> 6;
    const int m = lane & 15, q = lane >> 4;

    f32x4 acc[8];
    #pragma unroll
    for (int ni = 0; ni < 8; ni++) acc[ni] = (f32x4){0.f, 0.f, 0.f, 0.f};

    const unsigned short* arow = Xs + (w * 16 + m) * S2 + q * 8;
    const unsigned short* brow = Gs + m * S2 + q * 8;

    #pragma unroll
    for (int s = 0; s < 4; s++) {
        bf16x8 a = *(const bf16x8*)(arow + s * 32);
        #pragma unroll
        for (int ni = 0; ni < 8; ni++) {
            bf16x8 bb = *(const bf16x8*)(brow + ni * 16 * S2 + s * 32);
            acc[ni] = __builtin_amdgcn_mfma_f32_16x16x32_bf16(a, bb, acc[ni], 0, 0, 0);
        }
    }

    float* op = out + ((size_t)b * T + (size_t)chunk * ROWS2) * D;
    const int row0 = w * 16 + q * 4;
    #pragma unroll
    for (int ni = 0; ni < 8; ni++)
        #pragma unroll
        for (int r = 0; r < 4; r++)
            op[(row0 + r) * D + ni * 16 + m] = acc[ni][r];
}

extern "C" void kernel_launch(void* const* d_in, const int* in_sizes, int n_in,
                              void* d_out, int out_size, void* d_ws, size_t ws_size,
                              hipStream_t stream) {
    const float* x = (const float*)d_in[0];
    float* out = (float*)d_out;

    const size_t part_elems = (size_t)BATCH * CHUNKS * D * D;     // 4.19M bf16 (8.4 MB)
    unsigned short* part = (unsigned short*)d_ws;
    unsigned short* g = part + part_elems;                        // bf16 G, 128 KB

    k_gram<<<BATCH * CHUNKS, 256, 0, stream>>>(x, part);
    k_reduce_g<<<BATCH * D * D / 256, 256, 0, stream>>>(part, g);
    k_xg_mfma<<<BATCH * 64, 256, 0, stream>>>(x, g, out);
}